// Round 7
// baseline (453.622 us; speedup 1.0000x reference)
//
#include <hip/hip_runtime.h>
#include <hip/hip_cooperative_groups.h>
#include <stdint.h>

namespace cg = cooperative_groups;

#define USE_PARTITIONABLE 1

#define C_CLASSES 8192
#define N_ROWS 1280          // 256 live + 1024 stored
#define HALF_CROSS (C_CLASSES * N_ROWS / 2)
#define N_INTER 2097152      // 256*8192, one class
#define HALF_INTER (N_INTER / 2)
#define NB (1u << 20)        // bucket count for positive sort (key >> 12)
#define BSHIFT 12
#define CNT_CAP 24576        // per-positive count slots (P+1 <= this)
#define CNT_WORDS (CNT_CAP / 4)   // u8-packed, 6144 u32
#define CPB 8                // classes per kcross_fused block

#define MBLK 256             // mega-kernel blocks (1 per CU, cooperative)
#define MTHR 1024
#define EPB (N_INTER / MBLK) // 8192 elements per block
#define EPT (EPB / MTHR)     // 8
#define PLOC 192             // per-block positive cap (mean 82, 12 sigma)
#define BPB ((int)(NB / MBLK))    // 4096 buckets per block
#define WPB (CNT_WORDS / MBLK)    // 24 count-words per block

// ---------------- threefry2x32 (JAX-compatible) ----------------
__host__ __device__ __forceinline__ void tf2x32(unsigned k0, unsigned k1,
                                                unsigned c0, unsigned c1,
                                                unsigned& o0, unsigned& o1) {
  const unsigned ks2 = k0 ^ k1 ^ 0x1BD11BDAu;
  unsigned x0 = c0 + k0, x1 = c1 + k1;
#define TF_R(r) { x0 += x1; x1 = (x1 << (r)) | (x1 >> (32 - (r))); x1 ^= x0; }
  TF_R(13) TF_R(15) TF_R(26) TF_R(6)   x0 += k1;  x1 += ks2 + 1u;
  TF_R(17) TF_R(29) TF_R(16) TF_R(24)  x0 += ks2; x1 += k0 + 2u;
  TF_R(13) TF_R(15) TF_R(26) TF_R(6)   x0 += k0;  x1 += k1 + 3u;
  TF_R(17) TF_R(29) TF_R(16) TF_R(24)  x0 += k1;  x1 += ks2 + 4u;
  TF_R(13) TF_R(15) TF_R(26) TF_R(6)   x0 += ks2; x1 += k0 + 5u;
#undef TF_R
  o0 = x0; o1 = x1;
}

__device__ __forceinline__ unsigned rand_bits(unsigned k0, unsigned k1,
                                              unsigned p, unsigned half) {
#if USE_PARTITIONABLE
  (void)half;
  unsigned a, b; tf2x32(k0, k1, 0u, p, a, b);
  return a ^ b;
#else
  unsigned c0 = (p < half) ? p : (p - half);
  unsigned a, b; tf2x32(k0, k1, c0, c0 + half, a, b);
  return (p < half) ? a : b;
#endif
}

// XLA ErfInv32 (Giles)
__device__ __forceinline__ float erfinv_xla(float x) {
  float w = -log1pf(-x * x);
  float p;
  if (w < 5.0f) {
    w = w - 2.5f;
    p = 2.81022636e-08f;
    p = fmaf(p, w, 3.43273939e-07f);
    p = fmaf(p, w, -3.5233877e-06f);
    p = fmaf(p, w, -4.39150654e-06f);
    p = fmaf(p, w, 0.00021858087f);
    p = fmaf(p, w, -0.00125372503f);
    p = fmaf(p, w, -0.00417768164f);
    p = fmaf(p, w, 0.246640727f);
    p = fmaf(p, w, 1.50140941f);
  } else {
    w = sqrtf(w) - 3.0f;
    p = -0.000200214257f;
    p = fmaf(p, w, 0.000100950558f);
    p = fmaf(p, w, 0.00134934322f);
    p = fmaf(p, w, -0.00367342844f);
    p = fmaf(p, w, 0.00573950773f);
    p = fmaf(p, w, -0.0076224613f);
    p = fmaf(p, w, 0.00943887047f);
    p = fmaf(p, w, 1.00167406f);
    p = fmaf(p, w, 2.83297682f);
  }
  return p * x;
}

__device__ __forceinline__ float normal_from_bits(unsigned bits) {
  unsigned fb = (bits >> 9) | 0x3F800000u;
  float f = __uint_as_float(fb) - 1.0f;
  float u = fmaxf(-0.99999994f, f * 2.0f - 0.99999994f);
  return 1.41421356f * erfinv_xla(u);
}

__device__ __forceinline__ unsigned sortable_key(float sp) {
  unsigned b = __float_as_uint(sp);
  return (b & 0x80000000u) ? ~b : (b | 0x80000000u);  // ascending-order map
}

// ---------------- cross: fused perturb + per-class AP (8 classes/block) -----------
__global__ void __launch_bounds__(512, 6) kcross_fused(
    const float* __restrict__ outp, const float* __restrict__ tgt,
    const float* __restrict__ soutp, const float* __restrict__ stgt,
    float* __restrict__ prec_arr, float* __restrict__ pres_arr,
    unsigned k0, unsigned k1) {
  __shared__ float skey[N_ROWS][CPB + 1];        // 46,080 B (stride 9: conflict-free cols)
  __shared__ unsigned tmask32[N_ROWS / 4];       // 1,280 B (8 bits/row packed 4 rows/word)
  __shared__ unsigned short plist[CPB][64];      // 1,024 B
  __shared__ int pcnt[CPB];
  __shared__ unsigned short rankl[CPB][64];      // 1,024 B
  const int tid = threadIdx.x;
  const int c0 = blockIdx.x * CPB;

  for (int i = tid; i < N_ROWS / 4; i += 512) tmask32[i] = 0u;
  if (tid < CPB) pcnt[tid] = 0;
  __syncthreads();

  // phase 1: targets -> positivity bits + per-class positive lists
#pragma unroll
  for (int i = 0; i < 5; ++i) {
    int f = i * 512 + tid;                 // f < 2560 float4s
    int n = f >> 1, half = f & 1;
    const float* tp = (n < 256) ? (tgt + (size_t)n * C_CLASSES)
                                : (stgt + (size_t)(n - 256) * C_CLASSES);
    float4 tv = *(const float4*)(tp + c0 + half * 4);
    unsigned nib = (tv.x != 0.f ? 1u : 0u) | (tv.y != 0.f ? 2u : 0u) |
                   (tv.z != 0.f ? 4u : 0u) | (tv.w != 0.f ? 8u : 0u);
    if (nib) {
      atomicOr(&tmask32[n >> 2], nib << ((n & 3) * 8 + half * 4));
#pragma unroll
      for (int k = 0; k < 4; ++k) {
        if (nib & (1u << k)) {
          int j = half * 4 + k;
          int slot = atomicAdd(&pcnt[j], 1);
          if (slot < 64) plist[j][slot] = (unsigned short)n;
        }
      }
    }
  }
  __syncthreads();

  // phase 2: scores + RNG -> perturbed scores in LDS (bit-identical expr)
#pragma unroll
  for (int i = 0; i < 5; ++i) {
    int f = i * 512 + tid;
    int n = f >> 1, half = f & 1;
    const float* sp_ = (n < 256) ? (outp + (size_t)n * C_CLASSES)
                                 : (soutp + (size_t)(n - 256) * C_CLASSES);
    float4 sv = *(const float4*)(sp_ + c0 + half * 4);
    unsigned tmr = tmask32[n >> 2] >> ((n & 3) * 8);
    float vals[4] = {sv.x, sv.y, sv.z, sv.w};
#pragma unroll
    for (int k = 0; k < 4; ++k) {
      int j = half * 4 + k;
      unsigned p = (unsigned)((c0 + j) * N_ROWS + n);
      float nrm = normal_from_bits(rand_bits(k0, k1, p, HALF_CROSS));
      float tvf = ((tmr >> j) & 1u) ? 1.0f : 0.0f;
      skey[n][j] = vals[k] - 0.02f * (fabsf(nrm) * (tvf - 0.5f));
    }
  }
  __syncthreads();

  // phase 3: one wave per class; positives chunked x8, packed u16 counters
  const int j = tid >> 6, lane = tid & 63;
  int P = pcnt[j]; if (P > 64) P = 64;
  for (int base = 0; base < P; base += 8) {
    float spv[8]; int ipv[8];
#pragma unroll
    for (int k = 0; k < 8; ++k) {
      int pi = base + k;
      if (pi < P) { ipv[k] = plist[j][pi]; spv[k] = skey[ipv[k]][j]; }
      else { ipv[k] = 0x7fffffff; spv[k] = __int_as_float(0x7f800000); }  // +inf dummy
    }
    unsigned c16[4] = {0u, 0u, 0u, 0u};
    for (int s = 0; s < 20; ++s) {
      int n = lane + (s << 6);
      float x = skey[n][j];
#pragma unroll
      for (int k = 0; k < 8; ++k) {
        unsigned bb = (x > spv[k]) || ((x == spv[k]) & (n > ipv[k]));  // JAX tie rule
        c16[k >> 1] += bb << ((k & 1) * 16);
      }
    }
#pragma unroll
    for (int q = 0; q < 4; ++q) {
      unsigned v = c16[q];
      v += __shfl_down(v, 32); v += __shfl_down(v, 16); v += __shfl_down(v, 8);
      v += __shfl_down(v, 4);  v += __shfl_down(v, 2);  v += __shfl_down(v, 1);
      if (lane == 0) {
        int p0 = base + 2 * q;
        if (p0 < P)     rankl[j][p0]     = (unsigned short)(v & 0xFFFFu);
        if (p0 + 1 < P) rankl[j][p0 + 1] = (unsigned short)(v >> 16);
      }
    }
  }
  // epilogue: rank among positives + precision (same wave wrote rankl[j])
  double acc = 0.0;
  if (lane < P) {
    int ip = plist[j][lane];
    float spv0 = skey[ip][j];
    int kk = 1;
    for (int q = 0; q < P; ++q) {
      int iq = plist[j][q];
      float sq = skey[iq][j];
      kk += (sq > spv0) || ((sq == spv0) & (iq > ip));
    }
    unsigned rr = rankl[j][lane];
    float rw = (float)kk / 1280.0f;
    float ro = (float)(rr + 1u) / 1280.0f;
    acc = (double)(rw / ro);
  }
#pragma unroll
  for (int o = 32; o; o >>= 1) acc += __shfl_down(acc, o);
  if (lane == 0) {
    if (P > 0) { prec_arr[c0 + j] = (float)acc / ((float)P + 1e-5f); pres_arr[c0 + j] = 1.0f; }
    else       { prec_arr[c0 + j] = 0.0f;                            pres_arr[c0 + j] = 0.0f; }
  }
}

// ---------------- inter: single cooperative mega-kernel ----------------
__global__ void __launch_bounds__(1024) kinter_mega(
    const float* __restrict__ outp, const float* __restrict__ tgt,
    unsigned* __restrict__ hist_pos, unsigned* __restrict__ cursor,
    unsigned* __restrict__ bsh, unsigned* __restrict__ chunkTot,
    unsigned long long* __restrict__ t64, unsigned long long* __restrict__ spk64,
    unsigned* __restrict__ cnt_blocks, unsigned* __restrict__ tot,
    const float* __restrict__ prec_arr, const float* __restrict__ pres_arr,
    float* __restrict__ out, unsigned k0, unsigned k1) {
  cg::grid_group grid = cg::this_grid();
  __shared__ unsigned lkey[EPB];               // 32 KB — this block's keys, LDS-resident
  __shared__ unsigned cntp[CNT_WORDS];         // 24 KB — u8x4 packed counters
  __shared__ unsigned sc[MTHR];                // 4 KB — scan / reduce scratch
  __shared__ unsigned long long pk_loc[PLOC];  // 1.5 KB
  __shared__ int scnt;
  __shared__ unsigned uP;
  __shared__ double rd[1024];                  // 8 KB (phase VII)
  __shared__ unsigned lsum[1024];              // 4 KB (phase VII)
  const int tid = threadIdx.x;
  const int b = blockIdx.x;

  if (tid == 0) scnt = 0;
  __syncthreads();

  // ---- phase I: RNG + keys (to LDS) + positive collection ----
#pragma unroll
  for (int it = 0; it < EPT; ++it) {
    int loc = it * MTHR + tid;
    int n = b * EPB + loc;
    float t = tgt[n], sv = outp[n];
    float nrm = normal_from_bits(rand_bits(k0, k1, (unsigned)n, HALF_INTER));
    float sp = sv - 0.02f * (fabsf(nrm) * (t - 0.5f));
    unsigned key = sortable_key(sp);
    lkey[loc] = key;
    if (t != 0.0f) {
      int slot = atomicAdd(&scnt, 1);
      if (slot < PLOC) {
        pk_loc[slot] = ((unsigned long long)key << 21) | (unsigned)n;
        atomicAdd(&hist_pos[key >> BSHIFT], 1u);   // ~21k scattered atomics total
      }
    }
  }
  grid.sync();

  // ---- phase II-a: block-local bucket sums + 1024-wide scan ----
  uint4 hv = ((const uint4*)(hist_pos + (size_t)b * BPB))[tid];  // 4 buckets/thread
  unsigned tsum = hv.x + hv.y + hv.z + hv.w;
  sc[tid] = tsum;
  __syncthreads();
  for (int off = 1; off < MTHR; off <<= 1) {
    unsigned v = (tid >= off) ? sc[tid - off] : 0u;
    __syncthreads();
    sc[tid] += v;
    __syncthreads();
  }
  unsigned pre_t = sc[tid] - tsum;               // exclusive prefix within block
  if (tid == MTHR - 1) chunkTot[b] = sc[tid];
  grid.sync();

  // ---- phase II-b: global base; write cursor + bsh ----
  if (tid < MBLK) sc[tid] = chunkTot[tid];
  __syncthreads();
  for (int off = 1; off < MBLK; off <<= 1) {
    unsigned v = (tid < MBLK && tid >= off) ? sc[tid - off] : 0u;
    __syncthreads();
    if (tid < MBLK) sc[tid] += v;
    __syncthreads();
  }
  if (tid == 0) uP = sc[MBLK - 1];
  unsigned base_b = (b > 0) ? sc[b - 1] : 0u;
  unsigned s0 = base_b + pre_t;
  uint4 cu; cu.x = s0; cu.y = s0 + hv.x; cu.z = cu.y + hv.y; cu.w = cu.z + hv.z;
  ((uint4*)(cursor + (size_t)b * BPB))[tid] = cu;
  uint4 bs;
  bs.x = (cu.x << 8) | (hv.x > 255u ? 255u : hv.x);
  bs.y = (cu.y << 8) | (hv.y > 255u ? 255u : hv.y);
  bs.z = (cu.z << 8) | (hv.z > 255u ? 255u : hv.z);
  bs.w = (cu.w << 8) | (hv.w > 255u ? 255u : hv.w);
  ((uint4*)(bsh + (size_t)b * BPB))[tid] = bs;
  grid.sync();

  // ---- phase III: scatter positives (~21k scattered atomics) ----
  {
    int myScnt = scnt; if (myScnt > PLOC) myScnt = PLOC;
    if (tid < myScnt) {
      unsigned long long k64 = pk_loc[tid];
      unsigned bkt = (unsigned)(k64 >> 33);
      unsigned slot = atomicAdd(&cursor[bkt], 1u);
      t64[slot] = k64;
    }
  }
  grid.sync();

  // ---- phase IV: within-bucket ordering -> sorted spk64 ----
  const unsigned P = uP;
  {
    unsigned per = (P + MBLK - 1) / MBLK;     // <= ~86
    unsigned j0 = (unsigned)b * per;
    unsigned j = j0 + (unsigned)tid;
    if (tid < (int)per && j < P) {
      unsigned long long my = t64[j];
      unsigned bkt = (unsigned)(my >> 33);
      unsigned info = bsh[bkt];
      unsigned hp = info & 0xFFu;
      unsigned start = info >> 8;
      unsigned lt = 0;
      if (hp > 1) for (unsigned m = start; m < start + hp; ++m) lt += (t64[m] < my);
      spk64[start + lt] = my;
    }
  }
  grid.sync();

  // ---- phase V: per-element rank counting (keys from LDS) ----
  for (int i = tid; i < CNT_WORDS; i += MTHR) cntp[i] = 0;
  __syncthreads();
#pragma unroll
  for (int it = 0; it < EPT; ++it) {
    int loc = it * MTHR + tid;
    unsigned key = lkey[loc];
    unsigned n = (unsigned)(b * EPB + loc);
    unsigned long long k64 = ((unsigned long long)key << 21) | n;
    unsigned info = bsh[key >> BSHIFT];
    unsigned cntLess = info >> 8;
    unsigned hp = info & 0xFFu;
    if (hp) {
      unsigned start = cntLess;
      for (unsigned m = start; m < start + hp; ++m) cntLess += (spk64[m] < k64);
    }
    if (cntLess > CNT_CAP - 1) cntLess = CNT_CAP - 1;
    atomicAdd(&cntp[cntLess >> 2], 1u << ((cntLess & 3u) * 8u));
  }
  __syncthreads();
  {
    unsigned* dst = cnt_blocks + (size_t)b * CNT_WORDS;
    for (int i = tid; i < CNT_WORDS; i += MTHR) dst[i] = cntp[i];
  }
  grid.sync();

  // ---- phase VI: transpose-reduce per-block counts -> tot (block owns 24 words) ----
  {
    if (tid < WPB * 4) sc[tid] = 0u;
    __syncthreads();
    if (tid < 1008) {                       // 42 groups x 24 words
      int wl = tid % WPB;
      int blk0 = tid / WPB;
      unsigned a0 = 0, a1 = 0, a2 = 0, a3 = 0;
      for (int blk = blk0; blk < MBLK; blk += 42) {
        unsigned v = cnt_blocks[(size_t)blk * CNT_WORDS + b * WPB + wl];
        a0 += v & 0xFFu; a1 += (v >> 8) & 0xFFu; a2 += (v >> 16) & 0xFFu; a3 += v >> 24;
      }
      atomicAdd(&sc[wl * 4 + 0], a0);
      atomicAdd(&sc[wl * 4 + 1], a1);
      atomicAdd(&sc[wl * 4 + 2], a2);
      atomicAdd(&sc[wl * 4 + 3], a3);
    }
    __syncthreads();
    if (tid < WPB * 4) tot[b * WPB * 4 + tid] = sc[tid];   // tot[4*word+field] = slot count
  }
  grid.sync();

  // ---- phase VII: final combine (block 0 only) ----
  if (b != 0) return;
  const int CH = CNT_CAP / 1024;   // 24 slots per thread
  unsigned lv[CH];
  unsigned mys = 0;
#pragma unroll
  for (int i = 0; i < CH; ++i) { lv[i] = tot[tid * CH + i]; mys += lv[i]; }
  lsum[tid] = mys;
  __syncthreads();
  for (int off = 1; off < 1024; off <<= 1) {   // inclusive suffix scan
    unsigned v = (tid + off < 1024) ? lsum[tid + off] : 0u;
    __syncthreads();
    lsum[tid] += v;
    __syncthreads();
  }
  unsigned run = (tid < 1023) ? lsum[tid + 1] : 0u;
  double acc = 0.0;
#pragma unroll
  for (int i = CH - 1; i >= 0; --i) {
    unsigned idx = (unsigned)(tid * CH + i);
    unsigned r = run;                  // #elements in slots > idx
    if (idx < P) acc += (double)((float)(P - idx) / (float)(r + 1u));
    run += lv[i];
  }
  rd[tid] = acc;
  __syncthreads();
  for (int o = 512; o; o >>= 1) { if (tid < o) rd[tid] += rd[tid + o]; __syncthreads(); }
  double interSum = rd[0];
  __syncthreads();
  double a = 0.0, bb2 = 0.0;
  for (int i = tid; i < C_CLASSES; i += 1024) { a += (double)prec_arr[i]; bb2 += (double)pres_arr[i]; }
  rd[tid] = a;
  __syncthreads();
  for (int o = 512; o; o >>= 1) { if (tid < o) rd[tid] += rd[tid + o]; __syncthreads(); }
  double crossSum = rd[0];
  __syncthreads();
  rd[tid] = bb2;
  __syncthreads();
  for (int o = 512; o; o >>= 1) { if (tid < o) rd[tid] += rd[tid + o]; __syncthreads(); }
  if (tid == 0) {
    float pc = (float)rd[0];
    float denomC = pc > 0.0f ? pc : 1.0f;
    float crossLoss = 1.0f - (float)crossSum / denomC;
    float interPrec = (float)interSum / ((float)P + 1e-5f);
    float interLoss = 1.0f - interPrec;
    out[0] = 0.5f * crossLoss + 0.5f * interLoss;
  }
}

extern "C" void kernel_launch(void* const* d_in, const int* in_sizes, int n_in,
                              void* d_out, int out_size, void* d_ws, size_t ws_size,
                              hipStream_t stream) {
  (void)in_sizes; (void)n_in; (void)out_size; (void)ws_size;
  const float* outp  = (const float*)d_in[0];   // [256, 8192]
  const float* tgt   = (const float*)d_in[1];
  const float* soutp = (const float*)d_in[2];   // [1024, 8192]
  const float* stgt  = (const float*)d_in[3];
  float* dst = (float*)d_out;

  unsigned ck0, ck1, ik0, ik1;
#if USE_PARTITIONABLE
  tf2x32(0u, 42u, 0u, 0u, ck0, ck1);
  tf2x32(0u, 42u, 0u, 1u, ik0, ik1);
#else
  { unsigned a0, b0, a1, b1;
    tf2x32(0u, 42u, 0u, 2u, a0, b0);
    tf2x32(0u, 42u, 1u, 3u, a1, b1);
    ck0 = a0; ck1 = a1; ik0 = b0; ik1 = b1; }
#endif

  // ---- workspace carve-up (~19.1 MB) ----
  uint8_t* w = (uint8_t*)d_ws;
  size_t o = 0;
  unsigned* hist_pos   = (unsigned*)(w + o); o += (size_t)NB * 4;              // 4MB (memset)
  unsigned* cursor     = (unsigned*)(w + o); o += (size_t)NB * 4;              // 4MB
  unsigned* bsh        = (unsigned*)(w + o); o += (size_t)NB * 4;              // 4MB
  unsigned* chunkTot   = (unsigned*)(w + o); o += (size_t)MBLK * 4;
  unsigned long long* t64   = (unsigned long long*)(w + o); o += (size_t)32768 * 8; // 256KB
  unsigned long long* spk64 = (unsigned long long*)(w + o); o += (size_t)32768 * 8; // 256KB
  unsigned* cnt_blocks = (unsigned*)(w + o); o += (size_t)MBLK * CNT_WORDS * 4;     // 6.3MB
  unsigned* tot        = (unsigned*)(w + o); o += (size_t)CNT_CAP * 4;              // 96KB
  float*    prec_arr   = (float*)(w + o);    o += (size_t)C_CLASSES * 4;
  float*    pres_arr   = (float*)(w + o);    o += (size_t)C_CLASSES * 4;

  hipMemsetAsync(hist_pos, 0, (size_t)NB * 4, stream);

  kcross_fused<<<C_CLASSES / CPB, 512, 0, stream>>>(
      outp, tgt, soutp, stgt, prec_arr, pres_arr, ck0, ck1);

  void* margs[] = {(void*)&outp, (void*)&tgt, (void*)&hist_pos, (void*)&cursor,
                   (void*)&bsh, (void*)&chunkTot, (void*)&t64, (void*)&spk64,
                   (void*)&cnt_blocks, (void*)&tot, (void*)&prec_arr, (void*)&pres_arr,
                   (void*)&dst, (void*)&ik0, (void*)&ik1};
  hipLaunchCooperativeKernel((void*)kinter_mega, dim3(MBLK), dim3(MTHR), margs, 0, stream);
}